// Round 1
// baseline (110.871 us; speedup 1.0000x reference)
//
#include <hip/hip_runtime.h>
#include <math.h>

#define BB  16
#define TT  12
#define T2C 10
#define NN  300
#define DD  64
#define NWD (BB*T2C)   // 160 windows

typedef _Float16 f16;
typedef __attribute__((ext_vector_type(8)))  _Float16 f16x8;
typedef __attribute__((ext_vector_type(16))) float    f32x16;

#define KSM 136   // phase-1 LDS m-stride in f16 (128 rows + 8 pad)
#define KS  72    // Mh / Hl column stride in f16

static __device__ inline unsigned pk2(f16 a, f16 b) {
    union { f16 h[2]; unsigned u; } x; x.h[0] = a; x.h[1] = b; return x.u;
}

struct P1 {                       // phase-1 staging (39424 B)
    f16 Kti[64 * KSM];            // [c][m] feat*invn   (aliased later: Mw fp32 64x68)
    f16 Vtt[64 * KSM];            // [d][m] raw feat    (aliased later: tspp fp32 64x64)
    float sspart[128][8];
    float invrow[128];
};
struct P2 {                       // phase-2, 2 tile-groups (62976 B)
    float Ol[2][64 * 68];
    f16   Hl[2][64 * KS];
    float red[2][64][4][2];
    float rmax[2][64][4];
    float scls[2][64];
    float isls[2][64];
    float degp[2][64][4];
    float degs[2][64];
};

// ---------------------------------------------------------------------------
// One block per window (b,t2). 512 threads = 8 waves.
// Phase 1: stream the window's 900 contiguous feat rows in 8 epochs of 128,
//   computing row norms, packing K~ (feat*invn) and V (raw) to LDS, and
//   accumulating M_w = sum_m wf_m (x) feat_m via 32x32x16 MFMA; the 8 waves
//   split as (ci,di,kh): quadrant x m-half, partials reduced once at the end.
//   ksum (for deg) and invn of the 300 query rows stay in LDS.
// Phase 2: the verified k_U tail, 2 concurrent 64-row tile groups x 3 iters
//   (tiles 0..4): U^T = Mh . Q''^T, row-normalize, FFN (2 MFMA stages),
//   residual + LayerNorm, store. No global intermediates anywhere.
// ---------------------------------------------------------------------------
__global__ __launch_bounds__(512, 2) void k_fused(
        const float* __restrict__ feat,
        const float* __restrict__ weights,
        const float* __restrict__ w1,
        const float* __restrict__ b1,
        const float* __restrict__ w2,
        const float* __restrict__ b2,
        const float* __restrict__ gamma,
        const float* __restrict__ beta,
        float* __restrict__ out) {
    __shared__ union __align__(16) { P1 p1; P2 p2; } SH;
    __shared__ __align__(16) f16 Mh[64 * KS];      // persistent M_w fp16 [d][c]
    __shared__ __align__(16) float invq[NN + 4];   // invn of query rows
    __shared__ __align__(16) float ksumL[64];
    __shared__ __align__(16) float sigwL[64];

    int blk = blockIdx.x;
    // XCD-chunk swizzle: 160 % 8 == 0 -> bijective; XCD k gets windows [k*20, k*20+20)
    int wdw = (blk & 7) * (NWD / 8) + (blk >> 3);
    int t2 = wdw % T2C, b = wdw / T2C;
    int tid = threadIdx.x;
    int lane = tid & 63, l31 = lane & 31, lh = lane >> 5;
    int wv = tid >> 6;                 // 0..7
    int ci = wv & 1, di = (wv >> 1) & 1, kh = wv >> 2;
    int mr = (tid & 63) * 2;           // staging row pair 0..126
    int cb = (tid >> 6) * 8;           // staging 8-col block

    if (tid < 64) sigwL[tid] = 1.0f / (1.0f + expf(-weights[tid]));

    float sg[8];
    {
        float4 wv0 = *(const float4*)(weights + cb);
        float4 wv1 = *(const float4*)(weights + cb + 4);
        sg[0] = 1.f/(1.f+expf(-wv0.x)); sg[1] = 1.f/(1.f+expf(-wv0.y));
        sg[2] = 1.f/(1.f+expf(-wv0.z)); sg[3] = 1.f/(1.f+expf(-wv0.w));
        sg[4] = 1.f/(1.f+expf(-wv1.x)); sg[5] = 1.f/(1.f+expf(-wv1.y));
        sg[6] = 1.f/(1.f+expf(-wv1.z)); sg[7] = 1.f/(1.f+expf(-wv1.w));
    }

    // window rows are CONTIGUOUS: rows [baserow, baserow+900) of feat
    int baserow = (b * TT + t2) * NN;

    float tacc[8];
    #pragma unroll
    for (int i = 0; i < 8; i++) tacc[i] = 0.f;
    f32x16 acc;
    #pragma unroll
    for (int i = 0; i < 16; i++) acc[i] = 0.f;

#define LOADEP(EP, A, B) do { \
        int M0_ = (EP) * 128 + mr; \
        int g0_ = baserow + ((M0_ < 900) ? M0_ : 0); \
        int g1_ = baserow + ((M0_ + 1 < 900) ? (M0_ + 1) : 0); \
        float4 a0_ = *(const float4*)(feat + (size_t)g0_ * DD + cb); \
        float4 a1_ = *(const float4*)(feat + (size_t)g0_ * DD + cb + 4); \
        float4 b0_ = *(const float4*)(feat + (size_t)g1_ * DD + cb); \
        float4 b1_ = *(const float4*)(feat + (size_t)g1_ * DD + cb + 4); \
        A[0]=a0_.x; A[1]=a0_.y; A[2]=a0_.z; A[3]=a0_.w; \
        A[4]=a1_.x; A[5]=a1_.y; A[6]=a1_.z; A[7]=a1_.w; \
        B[0]=b0_.x; B[1]=b0_.y; B[2]=b0_.z; B[3]=b0_.w; \
        B[4]=b1_.x; B[5]=b1_.y; B[6]=b1_.z; B[7]=b1_.w; \
    } while (0)

    float a_cur[8], b_cur[8];
    LOADEP(0, a_cur, b_cur);

    #pragma unroll
    for (int ep = 0; ep < 8; ep++) {
        int M0 = ep * 128 + mr;
        bool ok0 = M0 < 900, ok1 = (M0 + 1) < 900;

        float ss0 = 0.f, ss1 = 0.f;
        #pragma unroll
        for (int i = 0; i < 8; i++) {
            float xa = a_cur[i] * sg[i], xb = b_cur[i] * sg[i];
            ss0 += xa * xa; ss1 += xb * xb;
        }
        SH.p1.sspart[mr][wv] = ss0;
        SH.p1.sspart[mr + 1][wv] = ss1;

        float a_nxt[8], b_nxt[8];
        if (ep < 7) LOADEP(ep + 1, a_nxt, b_nxt);   // prefetch under barrier chain

        __syncthreads();                  // sspart ready; prev-epoch MFMA reads done
        if (tid < 128) {
            float s = SH.p1.sspart[tid][0] + SH.p1.sspart[tid][1]
                    + SH.p1.sspart[tid][2] + SH.p1.sspart[tid][3]
                    + SH.p1.sspart[tid][4] + SH.p1.sspart[tid][5]
                    + SH.p1.sspart[tid][6] + SH.p1.sspart[tid][7];
            float in = 1.0f / fmaxf(sqrtf(s), 1e-12f);
            SH.p1.invrow[tid] = in;
            int M = ep * 128 + tid;
            if (M >= 600 && M < 900) invq[M - 600] = in;   // query-row invn
        }
        __syncthreads();
        float i0 = ok0 ? SH.p1.invrow[mr] : 0.f;
        float i1 = ok1 ? SH.p1.invrow[mr + 1] : 0.f;
        #pragma unroll
        for (int i = 0; i < 8; i++) {
            *(unsigned*)&SH.p1.Kti[(cb + i) * KSM + mr] =
                pk2((f16)(a_cur[i] * i0), (f16)(b_cur[i] * i1));
            *(unsigned*)&SH.p1.Vtt[(cb + i) * KSM + mr] =
                pk2((f16)a_cur[i], (f16)b_cur[i]);
            tacc[i] += a_cur[i] * i0 + b_cur[i] * i1;
        }
        __syncthreads();
        #pragma unroll
        for (int ks = 0; ks < 4; ks++) {
            f16x8 af = *(const f16x8*)&SH.p1.Kti[(ci*32+l31)*KSM + kh*64 + ks*16 + 8*lh];
            f16x8 bf = *(const f16x8*)&SH.p1.Vtt[(di*32+l31)*KSM + kh*64 + ks*16 + 8*lh];
            acc = __builtin_amdgcn_mfma_f32_32x32x16_f16(af, bf, acc, 0, 0, 0);
        }
        if (ep < 7) {
            #pragma unroll
            for (int i = 0; i < 8; i++) { a_cur[i] = a_nxt[i]; b_cur[i] = b_nxt[i]; }
        }
    }
#undef LOADEP

    // ---- phase boundary: reduce kh partials -> Mh fp16; tacc -> ksumL ----
    __syncthreads();                                   // last MFMA reads done
    float* Mw   = (float*)SH.p1.Kti;                   // 64x68 fp32 scratch
    float* tspp = (float*)SH.p1.Vtt;                   // 64x64 fp32 scratch
    if (kh == 1) {
        #pragma unroll
        for (int g4 = 0; g4 < 4; g4++)
            *(float4*)&Mw[(di*32+l31)*68 + ci*32 + 8*g4 + 4*lh] =
                make_float4(acc[4*g4+0], acc[4*g4+1], acc[4*g4+2], acc[4*g4+3]);
    }
    #pragma unroll
    for (int i = 0; i < 8; i++) tspp[(tid & 63) * 64 + cb + i] = tacc[i] * sg[i];
    __syncthreads();
    if (kh == 0) {
        #pragma unroll
        for (int g4 = 0; g4 < 4; g4++) {
            float4 m = *(const float4*)&Mw[(di*32+l31)*68 + ci*32 + 8*g4 + 4*lh];
            union { f16 h[4]; uint2 u; } p;
            p.h[0] = (f16)(acc[4*g4+0] + m.x);
            p.h[1] = (f16)(acc[4*g4+1] + m.y);
            p.h[2] = (f16)(acc[4*g4+2] + m.z);
            p.h[3] = (f16)(acc[4*g4+3] + m.w);
            *(uint2*)&Mh[(di*32+l31)*KS + ci*32 + 8*g4 + 4*lh] = p.u;
        }
    }
    if (tid < 64) {
        float s = 0.f;
        #pragma unroll 8
        for (int j = 0; j < 64; j++) s += tspp[j * 64 + tid];
        ksumL[tid] = s;
    }
    __syncthreads();    // Mh / ksumL / invq / sigwL ready; p1 region now dead

    // ------------------------------ phase 2 ------------------------------
    int grp = tid >> 8;                 // tile group 0/1
    int ltid = tid & 255;
    int wv_l = ltid >> 6;
    int nt = wv_l & 1, dt = wv_l >> 1;
    int ct = wv_l & 1, rt = wv_l >> 1;
    int r = ltid >> 2, q = ltid & 3, c0 = q * 16;
    int qrow0 = (b * TT + t2 + 2) * NN;

    // FFN weight A-frags direct from global (L1/L2-hot 16 KB arrays)
    f16x8 w1a[4], w2a[4];
    #pragma unroll
    for (int ks = 0; ks < 4; ks++) {
        f16x8 v1, v2;
        #pragma unroll
        for (int j = 0; j < 8; j++) {
            int drow = ks * 16 + 8 * lh + j;
            int hcol = ct * 32 + l31;
            v1[j] = (f16)w1[drow * DD + hcol];
            v2[j] = (f16)w2[drow * DD + hcol];
        }
        w1a[ks] = v1; w2a[ks] = v2;
    }

    for (int it = 0; it < 3; it++) {
        int tile = it * 2 + grp;        // group 0: tiles 0,2,4; group 1: 1,3,(5=idle)
        bool act = tile < 5;
        int n0 = tile * 64;

        __syncthreads();                // S0: previous iteration's reads done

        // Q'' B-frags: feat_q * sigw^2 * invn_q
        f16x8 qf[4];
        {
            int nloc = n0 + nt * 32 + l31;
            bool ok = act && (nloc < NN);
            int ni = ok ? nloc : 0;
            int gr = qrow0 + ni;
            float in = ok ? invq[ni] : 0.f;
            #pragma unroll
            for (int ks = 0; ks < 4; ks++) {
                int cc = ks * 16 + 8 * lh;
                float4 f0 = *(const float4*)(feat + (size_t)gr * DD + cc);
                float4 f1 = *(const float4*)(feat + (size_t)gr * DD + cc + 4);
                float4 s0 = *(const float4*)&sigwL[cc];
                float4 s1 = *(const float4*)&sigwL[cc + 4];
                f16x8 qv;
                qv[0] = (f16)(f0.x*s0.x*s0.x*in); qv[1] = (f16)(f0.y*s0.y*s0.y*in);
                qv[2] = (f16)(f0.z*s0.z*s0.z*in); qv[3] = (f16)(f0.w*s0.w*s0.w*in);
                qv[4] = (f16)(f1.x*s1.x*s1.x*in); qv[5] = (f16)(f1.y*s1.y*s1.y*in);
                qv[6] = (f16)(f1.z*s1.z*s1.z*in); qv[7] = (f16)(f1.w*s1.w*s1.w*in);
                qf[ks] = qv;
            }
        }

        // residual rows + invq
        int n = n0 + r;
        int nc = (n < NN) ? n : (NN - 1);
        size_t frow = ((size_t)qrow0 + nc) * DD;
        float fv[16];
        #pragma unroll
        for (int i = 0; i < 4; i++) {
            float4 f = *(const float4*)(feat + frow + c0 + 4 * i);
            fv[4*i+0] = f.x; fv[4*i+1] = f.y; fv[4*i+2] = f.z; fv[4*i+3] = f.w;
        }
        float invqr = invq[nc];

        // deg partials: wf_n . ksum
        {
            float p = 0.f;
            #pragma unroll
            for (int i = 0; i < 4; i++) {
                float4 s = *(const float4*)&sigwL[c0 + 4 * i];
                float4 k = *(const float4*)&ksumL[c0 + 4 * i];
                p += fv[4*i+0]*s.x*k.x + fv[4*i+1]*s.y*k.y
                   + fv[4*i+2]*s.z*k.z + fv[4*i+3]*s.w*k.w;
            }
            SH.p2.degp[grp][r][q] = p * invqr;
        }

        // U^T tile: D[d][n] = sum_c M(c,d) Q''(n,c)
        f32x16 ua;
        #pragma unroll
        for (int i = 0; i < 16; i++) ua[i] = 0.f;
        #pragma unroll
        for (int ks = 0; ks < 4; ks++) {
            f16x8 af = *(const f16x8*)&Mh[(dt*32+l31)*KS + ks*16 + 8*lh];
            ua = __builtin_amdgcn_mfma_f32_32x32x16_f16(af, qf[ks], ua, 0, 0, 0);
        }
        __syncthreads();                // S1: degp ready
        if (ltid < 64)
            SH.p2.degs[grp][ltid] = SH.p2.degp[grp][ltid][0] + SH.p2.degp[grp][ltid][1]
                                  + SH.p2.degp[grp][ltid][2] + SH.p2.degp[grp][ltid][3];
        __syncthreads();                // S2: degs ready

        {
            int nl = nt * 32 + l31;
            float dg = SH.p2.degs[grp][nl];
            float dinv = (dg == 0.f) ? 0.f : 1.f / dg;
            #pragma unroll
            for (int g4 = 0; g4 < 4; g4++)
                *(float4*)&SH.p2.Ol[grp][nl * 68 + dt * 32 + 8 * g4 + 4 * lh] =
                    make_float4(ua[4*g4+0]*dinv, ua[4*g4+1]*dinv,
                                ua[4*g4+2]*dinv, ua[4*g4+3]*dinv);
        }
        __syncthreads();                // S3: Ol ready

        {
            float mx = 0.f;
            #pragma unroll
            for (int i = 0; i < 16; i += 4) {
                float4 f = *(const float4*)&SH.p2.Ol[grp][r * 68 + c0 + i];
                mx = fmaxf(mx, fmaxf(fmaxf(fabsf(f.x), fabsf(f.y)),
                                     fmaxf(fabsf(f.z), fabsf(f.w))));
            }
            SH.p2.rmax[grp][r][q] = mx;
        }
        __syncthreads();                // S4
        if (q == 0) {
            float rm = fmaxf(fmaxf(SH.p2.rmax[grp][r][0], SH.p2.rmax[grp][r][1]),
                             fmaxf(SH.p2.rmax[grp][r][2], SH.p2.rmax[grp][r][3]));
            int e = 0;
            frexpf(rm, &e);
            SH.p2.scls[grp][r] = (rm > 1.f) ? exp2f((float)-e) : 1.f;
            SH.p2.isls[grp][r] = (rm > 1.f) ? exp2f((float)e) : 1.f;
        }
        __syncthreads();                // S5

        // FFN phase A: h_s^T = w1^T . A_s^T
        float sclrow = SH.p2.scls[grp][rt * 32 + l31];
        f32x16 hc;
        #pragma unroll
        for (int i = 0; i < 16; i++) hc[i] = 0.f;
        #pragma unroll
        for (int ks = 0; ks < 4; ks++) {
            const float* prw = &SH.p2.Ol[grp][(rt*32+l31)*68 + ks*16 + 8*lh];
            float4 pa = *(const float4*)prw;
            float4 pb = *(const float4*)(prw + 4);
            f16x8 bf;
            bf[0] = (f16)(pa.x * sclrow); bf[1] = (f16)(pa.y * sclrow);
            bf[2] = (f16)(pa.z * sclrow); bf[3] = (f16)(pa.w * sclrow);
            bf[4] = (f16)(pb.x * sclrow); bf[5] = (f16)(pb.y * sclrow);
            bf[6] = (f16)(pb.z * sclrow); bf[7] = (f16)(pb.w * sclrow);
            hc = __builtin_amdgcn_mfma_f32_32x32x16_f16(w1a[ks], bf, hc, 0, 0, 0);
        }
        #pragma unroll
        for (int g4 = 0; g4 < 4; g4++) {
            union { f16 h[4]; uint2 u; } p;
            #pragma unroll
            for (int i = 0; i < 4; i++) {
                int hcol = ct * 32 + 8 * g4 + 4 * lh + i;
                p.h[i] = (f16)fmaxf(hc[4 * g4 + i] + sclrow * b1[hcol], 0.f);
            }
            *(uint2*)&SH.p2.Hl[grp][(rt*32+l31)*KS + ct*32 + 8*g4 + 4*lh] = p.u;
        }
        __syncthreads();                // S6: Hl ready

        // FFN phase B: o_s^T = w2^T . h_s^T
        f32x16 oc;
        #pragma unroll
        for (int i = 0; i < 16; i++) oc[i] = 0.f;
        #pragma unroll
        for (int ks = 0; ks < 4; ks++) {
            f16x8 bf = *(const f16x8*)&SH.p2.Hl[grp][(rt*32+l31)*KS + ks*16 + 8*lh];
            oc = __builtin_amdgcn_mfma_f32_32x32x16_f16(w2a[ks], bf, oc, 0, 0, 0);
        }
        __syncthreads();                // S7
        #pragma unroll
        for (int g4 = 0; g4 < 4; g4++)
            *(float4*)&SH.p2.Ol[grp][(rt*32+l31)*68 + ct*32 + 8*g4 + 4*lh] =
                make_float4(oc[4*g4+0], oc[4*g4+1], oc[4*g4+2], oc[4*g4+3]);
        __syncthreads();                // S8: Ol(=o_s) ready

        // epilogue: s = o_s/s_n + b2 + residual; LayerNorm; guarded store
        float is = SH.p2.isls[grp][r];
        float v[16];
        float sum = 0.f;
        #pragma unroll
        for (int i = 0; i < 16; i++) {
            int c = c0 + i;
            float x = SH.p2.Ol[grp][r * 68 + c] * is + b2[c] + fv[i];
            v[i] = x; sum += x;
        }
        SH.p2.red[grp][r][q][0] = sum;
        __syncthreads();                // S9
        float mu = (SH.p2.red[grp][r][0][0] + SH.p2.red[grp][r][1][0]
                  + SH.p2.red[grp][r][2][0] + SH.p2.red[grp][r][3][0]) * (1.f / 64.f);
        float s2 = 0.f;
        #pragma unroll
        for (int i = 0; i < 16; i++) { float d = v[i] - mu; s2 += d * d; }
        SH.p2.red[grp][r][q][1] = s2;
        __syncthreads();                // S10
        float var = (SH.p2.red[grp][r][0][1] + SH.p2.red[grp][r][1][1]
                   + SH.p2.red[grp][r][2][1] + SH.p2.red[grp][r][3][1]) * (1.f / 64.f);
        float rs = rsqrtf(var + 1e-5f);
        if (act && n < NN) {
            size_t grow = (size_t)wdw * NN + n;
            #pragma unroll
            for (int i4 = 0; i4 < 4; i4++) {
                int c = c0 + 4 * i4;
                float4 g4v = *(const float4*)(gamma + c);
                float4 be  = *(const float4*)(beta + c);
                float4 o4;
                o4.x = (v[4*i4+0] - mu) * rs * g4v.x + be.x;
                o4.y = (v[4*i4+1] - mu) * rs * g4v.y + be.y;
                o4.z = (v[4*i4+2] - mu) * rs * g4v.z + be.z;
                o4.w = (v[4*i4+3] - mu) * rs * g4v.w + be.w;
                *(float4*)(out + grow * DD + c) = o4;
            }
        }
    }
}

// ---------------------------------------------------------------------------
extern "C" void kernel_launch(void* const* d_in, const int* in_sizes, int n_in,
                              void* d_out, int out_size, void* d_ws, size_t ws_size,
                              hipStream_t stream) {
    const float* feat    = (const float*)d_in[0];
    const float* weights = (const float*)d_in[1];
    const float* w1      = (const float*)d_in[2];
    const float* b1      = (const float*)d_in[3];
    const float* w2      = (const float*)d_in[4];
    const float* b2      = (const float*)d_in[5];
    const float* gamma   = (const float*)d_in[6];
    const float* beta    = (const float*)d_in[7];
    (void)in_sizes; (void)n_in; (void)out_size; (void)d_ws; (void)ws_size;

    k_fused<<<NWD, 512, 0, stream>>>(feat, weights, w1, b1, w2, b2, gamma, beta,
                                     (float*)d_out);
}

// Round 2
// 102.027 us; speedup vs baseline: 1.0867x; 1.0867x over previous
//
#include <hip/hip_runtime.h>
#include <math.h>

#define BB  16
#define TT  12
#define T2C 10
#define NN  300
#define DD  64
#define M3  900   // 3*NN
#define NW  (BB*T2C)

typedef _Float16 f16;
typedef __attribute__((ext_vector_type(8)))  _Float16 f16x8;
typedef __attribute__((ext_vector_type(16))) float    f32x16;

#define KS  72    // k_U fp16 row stride (144 B)
#define KSM 136   // k_pm fp16 m-stride (128 rows + 8 pad)

static __device__ inline unsigned pk2(f16 a, f16 b) {
    union { f16 h[2]; unsigned u; } x; x.h[0] = a; x.h[1] = b; return x.u;
}

// ---------------------------------------------------------------------------
// k_pm v2: one block per (b,t), 512 threads, 3 epochs of 128 rows with
// register prefetch. Per epoch: load feat -> row-norm invn (LDS reduce) ->
// pack Kti (feat*invn, [c][m]) + Vtt (raw, [d][m]) -> 8-wave MFMA (ci,di,kh)
// accumulate; kh partials reduced once at the end -> Mt fp32.
// tsum accumulated in registers (exact). blk == 192: sigw + w1/w2 -> fp16
// MFMA A-fragment order.
// ---------------------------------------------------------------------------
__global__ __launch_bounds__(512) void k_pm(const float* __restrict__ feat,
                                            const float* __restrict__ weights,
                                            const float* __restrict__ w1,
                                            const float* __restrict__ w2,
                                            float* __restrict__ sigw,
                                            float* __restrict__ invn,
                                            float* __restrict__ tsum,
                                            f16* __restrict__ w1f,
                                            f16* __restrict__ w2f,
                                            float* __restrict__ Mt) {
    int blk = blockIdx.x;
    int tid = threadIdx.x;

    if (blk == BB * TT) {
        if (tid < 64) sigw[tid] = 1.0f / (1.0f + expf(-weights[tid]));
        for (int p = tid; p < 1024; p += 512) {
            int lane = p & 63, s = p >> 6;
            int mat = s >> 3, loc = s & 7, ct = loc >> 2, ksv = loc & 3;
            int hcol = ct * 32 + (lane & 31);
            const float* w = mat ? w2 : w1;
            f16* dst = (mat ? w2f : w1f) + ((size_t)loc * 64 + lane) * 8;
            f16x8 v;
            #pragma unroll
            for (int j = 0; j < 8; j++) {
                int d = ksv * 16 + 8 * (lane >> 5) + j;
                v[j] = (f16)w[d * DD + hcol];
            }
            *(f16x8*)dst = v;
        }
        return;
    }

    __shared__ union __align__(16) {
        struct { f16 Kti[64 * KSM]; f16 Vtt[64 * KSM]; } s;   // 34816 B
        struct { float Mw[64 * 68]; float tspp[64 * 64]; } r; // 33792 B
    } SH;
    __shared__ float sspart[128][8];
    __shared__ float invrow[128];

    int bt = blk;
    int row0 = bt * NN;
    int wv = tid >> 6, lane = tid & 63;
    int l31 = lane & 31, lh = lane >> 5;
    int ci = wv & 1, di = (wv >> 1) & 1, kh = wv >> 2;
    int mr = (tid & 63) * 2;           // staging m-pair 0..126
    int cb = (tid >> 6) * 8;           // staging 8-col block

    float sg[8];
    {
        float4 wv0 = *(const float4*)(weights + cb);
        float4 wv1 = *(const float4*)(weights + cb + 4);
        sg[0] = 1.f/(1.f+expf(-wv0.x)); sg[1] = 1.f/(1.f+expf(-wv0.y));
        sg[2] = 1.f/(1.f+expf(-wv0.z)); sg[3] = 1.f/(1.f+expf(-wv0.w));
        sg[4] = 1.f/(1.f+expf(-wv1.x)); sg[5] = 1.f/(1.f+expf(-wv1.y));
        sg[6] = 1.f/(1.f+expf(-wv1.z)); sg[7] = 1.f/(1.f+expf(-wv1.w));
    }

    float tacc[8];
    #pragma unroll
    for (int i = 0; i < 8; i++) tacc[i] = 0.f;
    f32x16 acc;
    #pragma unroll
    for (int i = 0; i < 16; i++) acc[i] = 0.f;

#define LOADEP(EP, A, B) do { \
        int M0_ = (EP) * 128 + mr; \
        int g0_ = row0 + ((M0_ < NN) ? M0_ : 0); \
        int g1_ = row0 + ((M0_ + 1 < NN) ? (M0_ + 1) : 0); \
        float4 a0_ = *(const float4*)(feat + (size_t)g0_ * DD + cb); \
        float4 a1_ = *(const float4*)(feat + (size_t)g0_ * DD + cb + 4); \
        float4 b0_ = *(const float4*)(feat + (size_t)g1_ * DD + cb); \
        float4 b1_ = *(const float4*)(feat + (size_t)g1_ * DD + cb + 4); \
        A[0]=a0_.x; A[1]=a0_.y; A[2]=a0_.z; A[3]=a0_.w; \
        A[4]=a1_.x; A[5]=a1_.y; A[6]=a1_.z; A[7]=a1_.w; \
        B[0]=b0_.x; B[1]=b0_.y; B[2]=b0_.z; B[3]=b0_.w; \
        B[4]=b1_.x; B[5]=b1_.y; B[6]=b1_.z; B[7]=b1_.w; \
    } while (0)

    float a_cur[8], b_cur[8];
    LOADEP(0, a_cur, b_cur);

    #pragma unroll
    for (int ep = 0; ep < 3; ep++) {
        int M0 = ep * 128 + mr;
        bool ok0 = M0 < NN, ok1 = (M0 + 1) < NN;

        float ss0 = 0.f, ss1 = 0.f;
        #pragma unroll
        for (int i = 0; i < 8; i++) {
            float xa = a_cur[i] * sg[i], xb = b_cur[i] * sg[i];
            ss0 += xa * xa; ss1 += xb * xb;
        }
        sspart[mr][wv] = ss0;
        sspart[mr + 1][wv] = ss1;

        float a_nxt[8], b_nxt[8];
        if (ep < 2) LOADEP(ep + 1, a_nxt, b_nxt);   // prefetch under barrier chain

        __syncthreads();                  // sspart ready; prev-epoch MFMA reads done
        if (tid < 128) {
            float s = sspart[tid][0] + sspart[tid][1] + sspart[tid][2] + sspart[tid][3]
                    + sspart[tid][4] + sspart[tid][5] + sspart[tid][6] + sspart[tid][7];
            float in = 1.0f / fmaxf(sqrtf(s), 1e-12f);
            invrow[tid] = in;
            int grow = ep * 128 + tid;
            if (grow < NN) invn[row0 + grow] = in;
        }
        __syncthreads();
        float i0 = ok0 ? invrow[mr] : 0.f;
        float i1 = ok1 ? invrow[mr + 1] : 0.f;
        #pragma unroll
        for (int i = 0; i < 8; i++) {
            *(unsigned*)&SH.s.Kti[(cb + i) * KSM + mr] =
                pk2((f16)(a_cur[i] * i0), (f16)(b_cur[i] * i1));
            *(unsigned*)&SH.s.Vtt[(cb + i) * KSM + mr] =
                pk2((f16)a_cur[i], (f16)b_cur[i]);
            tacc[i] += a_cur[i] * i0 + b_cur[i] * i1;
        }
        __syncthreads();
        #pragma unroll
        for (int ks = 0; ks < 4; ks++) {
            f16x8 af = *(const f16x8*)&SH.s.Kti[(ci*32+l31)*KSM + kh*64 + ks*16 + 8*lh];
            f16x8 bf = *(const f16x8*)&SH.s.Vtt[(di*32+l31)*KSM + kh*64 + ks*16 + 8*lh];
            acc = __builtin_amdgcn_mfma_f32_32x32x16_f16(af, bf, acc, 0, 0, 0);
        }
        if (ep < 2) {
            #pragma unroll
            for (int i = 0; i < 8; i++) { a_cur[i] = a_nxt[i]; b_cur[i] = b_nxt[i]; }
        }
    }
#undef LOADEP

    // ---- tail: reduce kh partials -> Mt fp32; tacc -> tsum ----
    __syncthreads();                                   // last MFMA reads done
    if (kh == 1) {
        #pragma unroll
        for (int g = 0; g < 4; g++)
            *(float4*)&SH.r.Mw[(di*32+l31)*68 + ci*32 + 8*g + 4*lh] =
                make_float4(acc[4*g+0], acc[4*g+1], acc[4*g+2], acc[4*g+3]);
    }
    #pragma unroll
    for (int i = 0; i < 8; i++) SH.r.tspp[(tid & 63) * 64 + cb + i] = tacc[i] * sg[i];
    __syncthreads();
    if (kh == 0) {
        float* mb = Mt + (size_t)bt * 4096;
        #pragma unroll
        for (int g = 0; g < 4; g++) {
            float4 m = *(const float4*)&SH.r.Mw[(di*32+l31)*68 + ci*32 + 8*g + 4*lh];
            *(float4*)&mb[(di * 32 + l31) * 64 + ci * 32 + 8 * g + 4 * lh] =
                make_float4(acc[4*g+0] + m.x, acc[4*g+1] + m.y,
                            acc[4*g+2] + m.z, acc[4*g+3] + m.w);
        }
    }
    if (tid < 64) {
        float s = 0.f;
        #pragma unroll 8
        for (int j = 0; j < 64; j++) s += SH.r.tspp[j * 64 + tid];
        tsum[(size_t)bt * 64 + tid] = s;
    }
}

// ---------------------------------------------------------------------------
// k_U (r12-verified, unchanged): per (window, 64-row n-tile): M_w = 3-slab Mt
// sum -> fp16 Mh, U^T = Mh . Q''^T (4 MFMA), deg via tsum basis, Ol = U*dinv,
// then the verified FFN + residual + LayerNorm tail.
// ---------------------------------------------------------------------------
__global__ __launch_bounds__(256) void k_U(const float* __restrict__ feat,
                                           const float* __restrict__ sigw,
                                           const float* __restrict__ invn,
                                           const float* __restrict__ tsum,
                                           const float* __restrict__ Mt,
                                           const f16* __restrict__ w1f,
                                           const f16* __restrict__ w2f,
                                           const float* __restrict__ b1,
                                           const float* __restrict__ b2,
                                           const float* __restrict__ gamma,
                                           const float* __restrict__ beta,
                                           float* __restrict__ out) {
    __shared__ union __align__(16) {
        f16 Mh[64 * KS];
        f16 Hl[64 * KS];
    } MH;
    __shared__ float Ol[64 * 68];
    __shared__ float red[64][4][2];
    __shared__ float rmax[64][4];
    __shared__ float scls[64];
    __shared__ float isls[64];
    __shared__ float degp[64][4];
    __shared__ float degs[64];
    __shared__ float ksumL[64];

    int blk = blockIdx.x;
    int wdw = blk % NW;            // XCD swizzle
    int rb  = blk / NW;
    int t2 = wdw % T2C, b = wdw / T2C;
    int n0 = rb * 64;
    int qrow0 = (b * TT + t2 + 2) * NN;
    int tid = threadIdx.x;
    int wv = tid >> 6, lane = tid & 63;
    int l31 = lane & 31, lh = lane >> 5;
    int nt = wv & 1;
    int dt = wv >> 1;
    int ct = wv & 1, rt = wv >> 1;
    int r = tid >> 2, q = tid & 3, c0 = q * 16;

    f16x8 w1a[4], w2a[4];
    #pragma unroll
    for (int ks = 0; ks < 4; ks++) {
        w1a[ks] = *(const f16x8*)(w1f + ((size_t)(ct * 4 + ks) * 64 + lane) * 8);
        w2a[ks] = *(const f16x8*)(w2f + ((size_t)(ct * 4 + ks) * 64 + lane) * 8);
    }

    if (tid < 64) {
        const float* tp = tsum + (size_t)(b * TT + t2) * 64 + tid;
        ksumL[tid] = tp[0] + tp[64] + tp[128];
    }

    // Q'' B-frags: feat_q * sigw^2 * invn_q
    f16x8 qf[4];
    {
        int nloc = n0 + nt * 32 + l31;
        bool ok = nloc < NN;
        int gr = qrow0 + (ok ? nloc : 0);
        float in = ok ? invn[gr] : 0.f;
        #pragma unroll
        for (int ks = 0; ks < 4; ks++) {
            int cc = ks * 16 + 8 * lh;
            float4 f0 = *(const float4*)(feat + (size_t)gr * DD + cc);
            float4 f1 = *(const float4*)(feat + (size_t)gr * DD + cc + 4);
            float4 s0 = *(const float4*)(sigw + cc);
            float4 s1 = *(const float4*)(sigw + cc + 4);
            f16x8 qv;
            qv[0] = (f16)(f0.x * s0.x * s0.x * in); qv[1] = (f16)(f0.y * s0.y * s0.y * in);
            qv[2] = (f16)(f0.z * s0.z * s0.z * in); qv[3] = (f16)(f0.w * s0.w * s0.w * in);
            qv[4] = (f16)(f1.x * s1.x * s1.x * in); qv[5] = (f16)(f1.y * s1.y * s1.y * in);
            qv[6] = (f16)(f1.z * s1.z * s1.z * in); qv[7] = (f16)(f1.w * s1.w * s1.w * in);
            qf[ks] = qv;
        }
    }

    // M_w = sum of 3 Mt slabs (fp32)
    float ms[16];
    {
        const float* mtb = Mt + (size_t)(b * TT + t2) * 4096 + r * 64 + c0;
        #pragma unroll
        for (int i = 0; i < 4; i++) {
            float4 m0 = *(const float4*)(mtb + 4 * i);
            float4 m1 = *(const float4*)(mtb + 4096 + 4 * i);
            float4 m2 = *(const float4*)(mtb + 8192 + 4 * i);
            ms[4*i+0] = m0.x + m1.x + m2.x; ms[4*i+1] = m0.y + m1.y + m2.y;
            ms[4*i+2] = m0.z + m1.z + m2.z; ms[4*i+3] = m0.w + m1.w + m2.w;
        }
    }

    // residual feat rows + invq
    int n = n0 + r;
    int nc = (n < NN) ? n : (NN - 1);
    size_t frow = ((size_t)qrow0 + nc) * DD;
    float fv[16];
    #pragma unroll
    for (int i = 0; i < 4; i++) {
        float4 f = *(const float4*)(feat + frow + c0 + 4 * i);
        fv[4*i+0] = f.x; fv[4*i+1] = f.y; fv[4*i+2] = f.z; fv[4*i+3] = f.w;
    }
    float invq = invn[qrow0 + nc];

    __syncthreads();   // ksumL visible

    // deg partials
    {
        float p = 0.f;
        #pragma unroll
        for (int i = 0; i < 4; i++) {
            float4 s = *(const float4*)(sigw + c0 + 4 * i);
            float4 k = *(const float4*)(ksumL + c0 + 4 * i);
            p += fv[4*i+0] * s.x * k.x + fv[4*i+1] * s.y * k.y
               + fv[4*i+2] * s.z * k.z + fv[4*i+3] * s.w * k.w;
        }
        degp[r][q] = p * invq;
    }

    // Mh fp16 [d][c]
    #pragma unroll
    for (int hhalf = 0; hhalf < 2; hhalf++) {
        f16x8 v;
        #pragma unroll
        for (int j = 0; j < 8; j++) v[j] = (f16)ms[8 * hhalf + j];
        *(f16x8*)&MH.Mh[r * KS + c0 + 8 * hhalf] = v;
    }
    __syncthreads();

    if (tid < 64)
        degs[tid] = degp[tid][0] + degp[tid][1] + degp[tid][2] + degp[tid][3];

    // U^T tile: D[d][n] = sum_c M(c,d) Q''(n,c)
    f32x16 ua;
    #pragma unroll
    for (int i = 0; i < 16; i++) ua[i] = 0.f;
    #pragma unroll
    for (int ks = 0; ks < 4; ks++) {
        f16x8 af = *(const f16x8*)&MH.Mh[(dt * 32 + l31) * KS + ks * 16 + 8 * lh];
        ua = __builtin_amdgcn_mfma_f32_32x32x16_f16(af, qf[ks], ua, 0, 0, 0);
    }
    __syncthreads();

    // Ol[n][d] = U * dinv
    {
        int nl = nt * 32 + l31;
        float dg = degs[nl];
        float dinv = (dg == 0.f) ? 0.f : 1.f / dg;
        #pragma unroll
        for (int g = 0; g < 4; g++)
            *(float4*)&Ol[nl * 68 + dt * 32 + 8 * g + 4 * lh] =
                make_float4(ua[4*g+0] * dinv, ua[4*g+1] * dinv,
                            ua[4*g+2] * dinv, ua[4*g+3] * dinv);
    }
    __syncthreads();

    // per-row pow2 scale
    {
        float mx = 0.f;
        #pragma unroll
        for (int i = 0; i < 16; i += 4) {
            float4 f = *(const float4*)&Ol[r * 68 + c0 + i];
            mx = fmaxf(mx, fmaxf(fmaxf(fabsf(f.x), fabsf(f.y)),
                                 fmaxf(fabsf(f.z), fabsf(f.w))));
        }
        rmax[r][q] = mx;
    }
    __syncthreads();
    if (q == 0) {
        float rm = fmaxf(fmaxf(rmax[r][0], rmax[r][1]),
                         fmaxf(rmax[r][2], rmax[r][3]));
        int e = 0;
        frexpf(rm, &e);
        scls[r] = (rm > 1.f) ? exp2f((float)-e) : 1.f;
        isls[r] = (rm > 1.f) ? exp2f((float)e) : 1.f;
    }
    __syncthreads();

    // phase A: h_s^T = w1^T . A_s^T
    float sclrow = scls[rt * 32 + l31];
    f32x16 hc;
    #pragma unroll
    for (int i = 0; i < 16; i++) hc[i] = 0.f;
    #pragma unroll
    for (int ks = 0; ks < 4; ks++) {
        const float* prw = &Ol[(rt * 32 + l31) * 68 + ks * 16 + 8 * lh];
        float4 pa = *(const float4*)prw;
        float4 pb = *(const float4*)(prw + 4);
        f16x8 bf;
        bf[0] = (f16)(pa.x * sclrow); bf[1] = (f16)(pa.y * sclrow);
        bf[2] = (f16)(pa.z * sclrow); bf[3] = (f16)(pa.w * sclrow);
        bf[4] = (f16)(pb.x * sclrow); bf[5] = (f16)(pb.y * sclrow);
        bf[6] = (f16)(pb.z * sclrow); bf[7] = (f16)(pb.w * sclrow);
        hc = __builtin_amdgcn_mfma_f32_32x32x16_f16(w1a[ks], bf, hc, 0, 0, 0);
    }
    #pragma unroll
    for (int g = 0; g < 4; g++) {
        union { f16 h[4]; uint2 u; } p;
        #pragma unroll
        for (int i = 0; i < 4; i++) {
            int hcol = ct * 32 + 8 * g + 4 * lh + i;
            p.h[i] = (f16)fmaxf(hc[4 * g + i] + sclrow * b1[hcol], 0.f);
        }
        *(uint2*)&MH.Hl[(rt * 32 + l31) * KS + ct * 32 + 8 * g + 4 * lh] = p.u;
    }
    __syncthreads();

    // phase B: o_s^T = w2^T . h_s^T ; overwrite Ol
    f32x16 oc;
    #pragma unroll
    for (int i = 0; i < 16; i++) oc[i] = 0.f;
    #pragma unroll
    for (int ks = 0; ks < 4; ks++) {
        f16x8 bf = *(const f16x8*)&MH.Hl[(rt * 32 + l31) * KS + ks * 16 + 8 * lh];
        oc = __builtin_amdgcn_mfma_f32_32x32x16_f16(w2a[ks], bf, oc, 0, 0, 0);
    }
    __syncthreads();
    #pragma unroll
    for (int g = 0; g < 4; g++) {
        float4 o4 = make_float4(oc[4*g+0], oc[4*g+1], oc[4*g+2], oc[4*g+3]);
        *(float4*)&Ol[(rt * 32 + l31) * 68 + ct * 32 + 8 * g + 4 * lh] = o4;
    }
    __syncthreads();

    // epilogue: s = o_s/s_n + b2 + residual; LayerNorm; guarded store
    float is = isls[r];
    float v[16];
    float sum = 0.f;
    #pragma unroll
    for (int i = 0; i < 16; i++) {
        int c = c0 + i;
        float x = Ol[r * 68 + c] * is + b2[c] + fv[i];
        v[i] = x; sum += x;
    }
    red[r][q][0] = sum;
    __syncthreads();
    float mu = (red[r][0][0] + red[r][1][0] + red[r][2][0] + red[r][3][0]) * (1.f / 64.f);
    float s2 = 0.f;
    #pragma unroll
    for (int i = 0; i < 16; i++) { float d = v[i] - mu; s2 += d * d; }
    red[r][q][1] = s2;
    __syncthreads();
    float var = (red[r][0][1] + red[r][1][1] + red[r][2][1] + red[r][3][1]) * (1.f / 64.f);
    float rs = rsqrtf(var + 1e-5f);
    if (n < NN) {
        size_t grow = (size_t)wdw * NN + n;
        #pragma unroll
        for (int i4 = 0; i4 < 4; i4++) {
            int c = c0 + 4 * i4;
            float4 g4 = *(const float4*)(gamma + c);
            float4 be = *(const float4*)(beta + c);
            float4 o4;
            o4.x = (v[4*i4+0] - mu) * rs * g4.x + be.x;
            o4.y = (v[4*i4+1] - mu) * rs * g4.y + be.y;
            o4.z = (v[4*i4+2] - mu) * rs * g4.z + be.z;
            o4.w = (v[4*i4+3] - mu) * rs * g4.w + be.w;
            *(float4*)(out + grow * DD + c) = o4;
        }
    }
}

// ---------------------------------------------------------------------------
extern "C" void kernel_launch(void* const* d_in, const int* in_sizes, int n_in,
                              void* d_out, int out_size, void* d_ws, size_t ws_size,
                              hipStream_t stream) {
    const float* feat    = (const float*)d_in[0];
    const float* weights = (const float*)d_in[1];
    const float* w1      = (const float*)d_in[2];
    const float* b1      = (const float*)d_in[3];
    const float* w2      = (const float*)d_in[4];
    const float* b2      = (const float*)d_in[5];
    const float* gamma   = (const float*)d_in[6];
    const float* beta    = (const float*)d_in[7];
    float* out = (float*)d_out;

    float* sigw = (float*)d_ws;                 // 64
    float* invn = sigw + 64;                    // 57600
    float* tsum = invn + BB * TT * NN;          // 192*64 = 12288
    f16*   w1f  = (f16*)(tsum + BB * TT * DD);  // 4096 f16
    f16*   w2f  = w1f + 4096;                   // 4096 f16
    float* Mt   = (float*)(w2f + 4096);         // 192*4096 floats

    k_pm<<<BB * TT + 1, 512, 0, stream>>>(feat, weights, w1, w2, sigw, invn,
                                          tsum, w1f, w2f, Mt);
    k_U<<<NW * 5, 256, 0, stream>>>(feat, sigw, invn, tsum, Mt, w1f, w2f,
                                    b1, b2, gamma, beta, out);
}

// Round 3
// 101.199 us; speedup vs baseline: 1.0956x; 1.0082x over previous
//
#include <hip/hip_runtime.h>
#include <math.h>

#define BB  16
#define TT  12
#define T2C 10
#define NN  300
#define DD  64
#define M3  900   // 3*NN
#define NW  (BB*T2C)

typedef _Float16 f16;
typedef __attribute__((ext_vector_type(8)))  _Float16 f16x8;
typedef __attribute__((ext_vector_type(16))) float    f32x16;

#define KS  72    // k_U fp16 row stride (144 B)
#define KSM 136   // k_pm fp16 m-stride (128 rows + 8 pad)

static __device__ inline unsigned pk2(f16 a, f16 b) {
    union { f16 h[2]; unsigned u; } x; x.h[0] = a; x.h[1] = b; return x.u;
}

// ---------------------------------------------------------------------------
// k_pm v3: one block per (b,t), 512 threads, 3 epochs of 128 rows with
// register prefetch. Row-norm reduce: transposed sspart[8][128], every thread
// reads its own 8 partials (sequential order == old tid<128 path, bit-exact)
// -> 2 barriers/epoch instead of 3, no serialized reduce phase.
// 8-wave MFMA (ci,di,kh); kh partials reduced once at the end -> Mt fp32.
// blk == 192: sigw + w1/w2 -> fp16 MFMA A-fragment order.
// ---------------------------------------------------------------------------
__global__ __launch_bounds__(512) void k_pm(const float* __restrict__ feat,
                                            const float* __restrict__ weights,
                                            const float* __restrict__ w1,
                                            const float* __restrict__ w2,
                                            float* __restrict__ sigw,
                                            float* __restrict__ invn,
                                            float* __restrict__ tsum,
                                            f16* __restrict__ w1f,
                                            f16* __restrict__ w2f,
                                            float* __restrict__ Mt) {
    int blk = blockIdx.x;
    int tid = threadIdx.x;

    if (blk == BB * TT) {
        if (tid < 64) sigw[tid] = 1.0f / (1.0f + expf(-weights[tid]));
        for (int p = tid; p < 1024; p += 512) {
            int lane = p & 63, s = p >> 6;
            int mat = s >> 3, loc = s & 7, ct = loc >> 2, ksv = loc & 3;
            int hcol = ct * 32 + (lane & 31);
            const float* w = mat ? w2 : w1;
            f16* dst = (mat ? w2f : w1f) + ((size_t)loc * 64 + lane) * 8;
            f16x8 v;
            #pragma unroll
            for (int j = 0; j < 8; j++) {
                int d = ksv * 16 + 8 * (lane >> 5) + j;
                v[j] = (f16)w[d * DD + hcol];
            }
            *(f16x8*)dst = v;
        }
        return;
    }

    __shared__ union __align__(16) {
        struct { f16 Kti[64 * KSM]; f16 Vtt[64 * KSM]; } s;   // 34816 B
        struct { float Mw[64 * 68]; float tspp[64 * 64]; } r; // 33792 B
    } SH;
    __shared__ float sspartT[8][128];   // [wv][row] row-norm partials

    int bt = blk;
    int row0 = bt * NN;
    int wv = tid >> 6, lane = tid & 63;
    int l31 = lane & 31, lh = lane >> 5;
    int ci = wv & 1, di = (wv >> 1) & 1, kh = wv >> 2;
    int mr = (tid & 63) * 2;           // staging m-pair 0..126
    int cb = (tid >> 6) * 8;           // staging 8-col block

    float sg[8];
    {
        float4 wv0 = *(const float4*)(weights + cb);
        float4 wv1 = *(const float4*)(weights + cb + 4);
        sg[0] = 1.f/(1.f+expf(-wv0.x)); sg[1] = 1.f/(1.f+expf(-wv0.y));
        sg[2] = 1.f/(1.f+expf(-wv0.z)); sg[3] = 1.f/(1.f+expf(-wv0.w));
        sg[4] = 1.f/(1.f+expf(-wv1.x)); sg[5] = 1.f/(1.f+expf(-wv1.y));
        sg[6] = 1.f/(1.f+expf(-wv1.z)); sg[7] = 1.f/(1.f+expf(-wv1.w));
    }

    float tacc[8];
    #pragma unroll
    for (int i = 0; i < 8; i++) tacc[i] = 0.f;
    f32x16 acc;
    #pragma unroll
    for (int i = 0; i < 16; i++) acc[i] = 0.f;

#define LOADEP(EP, A, B) do { \
        int M0_ = (EP) * 128 + mr; \
        int g0_ = row0 + ((M0_ < NN) ? M0_ : 0); \
        int g1_ = row0 + ((M0_ + 1 < NN) ? (M0_ + 1) : 0); \
        float4 a0_ = *(const float4*)(feat + (size_t)g0_ * DD + cb); \
        float4 a1_ = *(const float4*)(feat + (size_t)g0_ * DD + cb + 4); \
        float4 b0_ = *(const float4*)(feat + (size_t)g1_ * DD + cb); \
        float4 b1_ = *(const float4*)(feat + (size_t)g1_ * DD + cb + 4); \
        A[0]=a0_.x; A[1]=a0_.y; A[2]=a0_.z; A[3]=a0_.w; \
        A[4]=a1_.x; A[5]=a1_.y; A[6]=a1_.z; A[7]=a1_.w; \
        B[0]=b0_.x; B[1]=b0_.y; B[2]=b0_.z; B[3]=b0_.w; \
        B[4]=b1_.x; B[5]=b1_.y; B[6]=b1_.z; B[7]=b1_.w; \
    } while (0)

    float a_cur[8], b_cur[8];
    LOADEP(0, a_cur, b_cur);

    #pragma unroll
    for (int ep = 0; ep < 3; ep++) {
        int M0 = ep * 128 + mr;
        bool ok0 = M0 < NN, ok1 = (M0 + 1) < NN;   // NN even, M0 even -> ok0==ok1

        float ss0 = 0.f, ss1 = 0.f;
        #pragma unroll
        for (int i = 0; i < 8; i++) {
            float xa = a_cur[i] * sg[i], xb = b_cur[i] * sg[i];
            ss0 += xa * xa; ss1 += xb * xb;
        }
        sspartT[wv][mr] = ss0;
        sspartT[wv][mr + 1] = ss1;

        float a_nxt[8], b_nxt[8];
        if (ep < 2) LOADEP(ep + 1, a_nxt, b_nxt);   // prefetch under barrier chain

        __syncthreads();     // A: sspart ready; prev-epoch MFMA reads drained
        // every thread reduces its own row pair (order == old sequential sum)
        float2 p0 = *(const float2*)&sspartT[0][mr];
        float s0 = p0.x, s1 = p0.y;
        #pragma unroll
        for (int j = 1; j < 8; j++) {
            float2 pj = *(const float2*)&sspartT[j][mr];
            s0 += pj.x; s1 += pj.y;
        }
        float in0 = 1.0f / fmaxf(sqrtf(s0), 1e-12f);
        float in1 = 1.0f / fmaxf(sqrtf(s1), 1e-12f);
        if (wv == 0 && ok0) *(float2*)&invn[row0 + M0] = make_float2(in0, in1);
        float i0 = ok0 ? in0 : 0.f;
        float i1 = ok1 ? in1 : 0.f;
        #pragma unroll
        for (int i = 0; i < 8; i++) {
            *(unsigned*)&SH.s.Kti[(cb + i) * KSM + mr] =
                pk2((f16)(a_cur[i] * i0), (f16)(b_cur[i] * i1));
            *(unsigned*)&SH.s.Vtt[(cb + i) * KSM + mr] =
                pk2((f16)a_cur[i], (f16)b_cur[i]);
            tacc[i] += a_cur[i] * i0 + b_cur[i] * i1;
        }
        __syncthreads();     // B: pack ready
        #pragma unroll
        for (int ks = 0; ks < 4; ks++) {
            f16x8 af = *(const f16x8*)&SH.s.Kti[(ci*32+l31)*KSM + kh*64 + ks*16 + 8*lh];
            f16x8 bf = *(const f16x8*)&SH.s.Vtt[(di*32+l31)*KSM + kh*64 + ks*16 + 8*lh];
            acc = __builtin_amdgcn_mfma_f32_32x32x16_f16(af, bf, acc, 0, 0, 0);
        }
        if (ep < 2) {
            #pragma unroll
            for (int i = 0; i < 8; i++) { a_cur[i] = a_nxt[i]; b_cur[i] = b_nxt[i]; }
        }
    }
#undef LOADEP

    // ---- tail: reduce kh partials -> Mt fp32; tacc -> tsum ----
    __syncthreads();                                   // last MFMA reads done
    if (kh == 1) {
        #pragma unroll
        for (int g = 0; g < 4; g++)
            *(float4*)&SH.r.Mw[(di*32+l31)*68 + ci*32 + 8*g + 4*lh] =
                make_float4(acc[4*g+0], acc[4*g+1], acc[4*g+2], acc[4*g+3]);
    }
    #pragma unroll
    for (int i = 0; i < 8; i++) SH.r.tspp[(tid & 63) * 64 + cb + i] = tacc[i] * sg[i];
    __syncthreads();
    if (kh == 0) {
        float* mb = Mt + (size_t)bt * 4096;
        #pragma unroll
        for (int g = 0; g < 4; g++) {
            float4 m = *(const float4*)&SH.r.Mw[(di*32+l31)*68 + ci*32 + 8*g + 4*lh];
            *(float4*)&mb[(di * 32 + l31) * 64 + ci * 32 + 8 * g + 4 * lh] =
                make_float4(acc[4*g+0] + m.x, acc[4*g+1] + m.y,
                            acc[4*g+2] + m.z, acc[4*g+3] + m.w);
        }
    }
    if (tid < 64) {
        float s = 0.f;
        #pragma unroll 8
        for (int j = 0; j < 64; j++) s += SH.r.tspp[j * 64 + tid];
        tsum[(size_t)bt * 64 + tid] = s;
    }
}

// ---------------------------------------------------------------------------
// k_U v2: same math as the verified r12 kernel, but every 4-partial row
// reduction (deg, row-max, LayerNorm mu/var) is an ORDERED intra-quad
// __shfl sum (lanes 4r..4r+3, bit-identical order to the old LDS path).
// Barrier chain cut 11 -> 6; red/rmax/degp/isls LDS arrays removed.
// ---------------------------------------------------------------------------
__global__ __launch_bounds__(256) void k_U(const float* __restrict__ feat,
                                           const float* __restrict__ sigw,
                                           const float* __restrict__ invn,
                                           const float* __restrict__ tsum,
                                           const float* __restrict__ Mt,
                                           const f16* __restrict__ w1f,
                                           const f16* __restrict__ w2f,
                                           const float* __restrict__ b1,
                                           const float* __restrict__ b2,
                                           const float* __restrict__ gamma,
                                           const float* __restrict__ beta,
                                           float* __restrict__ out) {
    __shared__ union __align__(16) {
        f16 Mh[64 * KS];
        f16 Hl[64 * KS];
    } MH;
    __shared__ float Ol[64 * 68];
    __shared__ float scls[64];
    __shared__ float degs[64];
    __shared__ float ksumL[64];

    int blk = blockIdx.x;
    int wdw = blk % NW;            // XCD swizzle
    int rb  = blk / NW;
    int t2 = wdw % T2C, b = wdw / T2C;
    int n0 = rb * 64;
    int qrow0 = (b * TT + t2 + 2) * NN;
    int tid = threadIdx.x;
    int wv = tid >> 6, lane = tid & 63;
    int l31 = lane & 31, lh = lane >> 5;
    int nt = wv & 1;
    int dt = wv >> 1;
    int ct = wv & 1, rt = wv >> 1;
    int r = tid >> 2, q = tid & 3, c0 = q * 16;
    int lq = lane & ~3;            // quad base lane (within wave)

    f16x8 w1a[4], w2a[4];
    #pragma unroll
    for (int ks = 0; ks < 4; ks++) {
        w1a[ks] = *(const f16x8*)(w1f + ((size_t)(ct * 4 + ks) * 64 + lane) * 8);
        w2a[ks] = *(const f16x8*)(w2f + ((size_t)(ct * 4 + ks) * 64 + lane) * 8);
    }

    if (tid < 64) {
        const float* tp = tsum + (size_t)(b * TT + t2) * 64 + tid;
        ksumL[tid] = tp[0] + tp[64] + tp[128];
    }

    // Q'' B-frags: feat_q * sigw^2 * invn_q
    f16x8 qf[4];
    {
        int nloc = n0 + nt * 32 + l31;
        bool ok = nloc < NN;
        int gr = qrow0 + (ok ? nloc : 0);
        float in = ok ? invn[gr] : 0.f;
        #pragma unroll
        for (int ks = 0; ks < 4; ks++) {
            int cc = ks * 16 + 8 * lh;
            float4 f0 = *(const float4*)(feat + (size_t)gr * DD + cc);
            float4 f1 = *(const float4*)(feat + (size_t)gr * DD + cc + 4);
            float4 s0 = *(const float4*)(sigw + cc);
            float4 s1 = *(const float4*)(sigw + cc + 4);
            f16x8 qv;
            qv[0] = (f16)(f0.x * s0.x * s0.x * in); qv[1] = (f16)(f0.y * s0.y * s0.y * in);
            qv[2] = (f16)(f0.z * s0.z * s0.z * in); qv[3] = (f16)(f0.w * s0.w * s0.w * in);
            qv[4] = (f16)(f1.x * s1.x * s1.x * in); qv[5] = (f16)(f1.y * s1.y * s1.y * in);
            qv[6] = (f16)(f1.z * s1.z * s1.z * in); qv[7] = (f16)(f1.w * s1.w * s1.w * in);
            qf[ks] = qv;
        }
    }

    // M_w = sum of 3 Mt slabs (fp32)
    float ms[16];
    {
        const float* mtb = Mt + (size_t)(b * TT + t2) * 4096 + r * 64 + c0;
        #pragma unroll
        for (int i = 0; i < 4; i++) {
            float4 m0 = *(const float4*)(mtb + 4 * i);
            float4 m1 = *(const float4*)(mtb + 4096 + 4 * i);
            float4 m2 = *(const float4*)(mtb + 8192 + 4 * i);
            ms[4*i+0] = m0.x + m1.x + m2.x; ms[4*i+1] = m0.y + m1.y + m2.y;
            ms[4*i+2] = m0.z + m1.z + m2.z; ms[4*i+3] = m0.w + m1.w + m2.w;
        }
    }

    // residual feat rows + invq
    int n = n0 + r;
    int nc = (n < NN) ? n : (NN - 1);
    size_t frow = ((size_t)qrow0 + nc) * DD;
    float fv[16];
    #pragma unroll
    for (int i = 0; i < 4; i++) {
        float4 f = *(const float4*)(feat + frow + c0 + 4 * i);
        fv[4*i+0] = f.x; fv[4*i+1] = f.y; fv[4*i+2] = f.z; fv[4*i+3] = f.w;
    }
    float invq = invn[qrow0 + nc];

    __syncthreads();   // #1: ksumL visible

    // deg: per-thread partial -> ordered quad shuffle sum -> degs[r]
    {
        float p = 0.f;
        #pragma unroll
        for (int i = 0; i < 4; i++) {
            float4 s = *(const float4*)(sigw + c0 + 4 * i);
            float4 k = *(const float4*)(ksumL + c0 + 4 * i);
            p += fv[4*i+0] * s.x * k.x + fv[4*i+1] * s.y * k.y
               + fv[4*i+2] * s.z * k.z + fv[4*i+3] * s.w * k.w;
        }
        p *= invq;
        float dsum = __shfl(p, lq + 0) + __shfl(p, lq + 1)
                   + __shfl(p, lq + 2) + __shfl(p, lq + 3);
        if (q == 0) degs[r] = dsum;
    }

    // Mh fp16 [d][c]
    #pragma unroll
    for (int hhalf = 0; hhalf < 2; hhalf++) {
        f16x8 v;
        #pragma unroll
        for (int j = 0; j < 8; j++) v[j] = (f16)ms[8 * hhalf + j];
        *(f16x8*)&MH.Mh[r * KS + c0 + 8 * hhalf] = v;
    }
    __syncthreads();   // #2: Mh + degs ready

    // U^T tile: D[d][n] = sum_c M(c,d) Q''(n,c)
    f32x16 ua;
    #pragma unroll
    for (int i = 0; i < 16; i++) ua[i] = 0.f;
    #pragma unroll
    for (int ks = 0; ks < 4; ks++) {
        f16x8 af = *(const f16x8*)&MH.Mh[(dt * 32 + l31) * KS + ks * 16 + 8 * lh];
        ua = __builtin_amdgcn_mfma_f32_32x32x16_f16(af, qf[ks], ua, 0, 0, 0);
    }

    // Ol[n][d] = U * dinv
    {
        int nl = nt * 32 + l31;
        float dg = degs[nl];
        float dinv = (dg == 0.f) ? 0.f : 1.f / dg;
        #pragma unroll
        for (int g = 0; g < 4; g++)
            *(float4*)&Ol[nl * 68 + dt * 32 + 8 * g + 4 * lh] =
                make_float4(ua[4*g+0] * dinv, ua[4*g+1] * dinv,
                            ua[4*g+2] * dinv, ua[4*g+3] * dinv);
    }
    __syncthreads();   // #3: Ol ready

    // per-row pow2 scale: quad shuffle max (order == old fmax tree), all lanes
    // compute scl/is locally; scls needed in LDS for the wave-mapped FFN reader
    float is;
    {
        float mx = 0.f;
        #pragma unroll
        for (int i = 0; i < 16; i += 4) {
            float4 f = *(const float4*)&Ol[r * 68 + c0 + i];
            mx = fmaxf(mx, fmaxf(fmaxf(fabsf(f.x), fabsf(f.y)),
                                 fmaxf(fabsf(f.z), fabsf(f.w))));
        }
        float rm = fmaxf(fmaxf(__shfl(mx, lq + 0), __shfl(mx, lq + 1)),
                         fmaxf(__shfl(mx, lq + 2), __shfl(mx, lq + 3)));
        int e = 0;
        frexpf(rm, &e);
        float scl = (rm > 1.f) ? exp2f((float)-e) : 1.f;
        is = (rm > 1.f) ? exp2f((float)e) : 1.f;
        if (q == 0) scls[r] = scl;
    }
    __syncthreads();   // #4: scls ready

    // phase A: h_s^T = w1^T . A_s^T
    float sclrow = scls[rt * 32 + l31];
    f32x16 hc;
    #pragma unroll
    for (int i = 0; i < 16; i++) hc[i] = 0.f;
    #pragma unroll
    for (int ks = 0; ks < 4; ks++) {
        const float* prw = &Ol[(rt * 32 + l31) * 68 + ks * 16 + 8 * lh];
        float4 pa = *(const float4*)prw;
        float4 pb = *(const float4*)(prw + 4);
        f16x8 bf;
        bf[0] = (f16)(pa.x * sclrow); bf[1] = (f16)(pa.y * sclrow);
        bf[2] = (f16)(pa.z * sclrow); bf[3] = (f16)(pa.w * sclrow);
        bf[4] = (f16)(pb.x * sclrow); bf[5] = (f16)(pb.y * sclrow);
        bf[6] = (f16)(pb.z * sclrow); bf[7] = (f16)(pb.w * sclrow);
        hc = __builtin_amdgcn_mfma_f32_32x32x16_f16(w1a[ks], bf, hc, 0, 0, 0);
    }
    #pragma unroll
    for (int g = 0; g < 4; g++) {
        union { f16 h[4]; uint2 u; } p;
        #pragma unroll
        for (int i = 0; i < 4; i++) {
            int hcol = ct * 32 + 8 * g + 4 * lh + i;
            p.h[i] = (f16)fmaxf(hc[4 * g + i] + sclrow * b1[hcol], 0.f);
        }
        *(uint2*)&MH.Hl[(rt * 32 + l31) * KS + ct * 32 + 8 * g + 4 * lh] = p.u;
    }
    __syncthreads();   // #5: Hl ready (also: all phase-A Ol reads done)

    // phase B: o_s^T = w2^T . h_s^T ; overwrite Ol (safe after #5, no barrier)
    f32x16 oc;
    #pragma unroll
    for (int i = 0; i < 16; i++) oc[i] = 0.f;
    #pragma unroll
    for (int ks = 0; ks < 4; ks++) {
        f16x8 bf = *(const f16x8*)&MH.Hl[(rt * 32 + l31) * KS + ks * 16 + 8 * lh];
        oc = __builtin_amdgcn_mfma_f32_32x32x16_f16(w2a[ks], bf, oc, 0, 0, 0);
    }
    #pragma unroll
    for (int g = 0; g < 4; g++) {
        float4 o4 = make_float4(oc[4*g+0], oc[4*g+1], oc[4*g+2], oc[4*g+3]);
        *(float4*)&Ol[(rt * 32 + l31) * 68 + ct * 32 + 8 * g + 4 * lh] = o4;
    }
    __syncthreads();   // #6: Ol(=o_s) ready

    // epilogue: s = o_s/s_n + b2 + residual; LayerNorm via ordered quad
    // shuffles (order == old red[r][0..3] sums); guarded store
    float v[16];
    float sum = 0.f;
    #pragma unroll
    for (int i = 0; i < 16; i++) {
        int c = c0 + i;
        float x = Ol[r * 68 + c] * is + b2[c] + fv[i];
        v[i] = x; sum += x;
    }
    float musum = __shfl(sum, lq + 0) + __shfl(sum, lq + 1)
                + __shfl(sum, lq + 2) + __shfl(sum, lq + 3);
    float mu = musum * (1.f / 64.f);
    float s2 = 0.f;
    #pragma unroll
    for (int i = 0; i < 16; i++) { float d = v[i] - mu; s2 += d * d; }
    float vsum = __shfl(s2, lq + 0) + __shfl(s2, lq + 1)
               + __shfl(s2, lq + 2) + __shfl(s2, lq + 3);
    float var = vsum * (1.f / 64.f);
    float rs = rsqrtf(var + 1e-5f);
    if (n < NN) {
        size_t grow = (size_t)wdw * NN + n;
        #pragma unroll
        for (int i4 = 0; i4 < 4; i4++) {
            int c = c0 + 4 * i4;
            float4 g4 = *(const float4*)(gamma + c);
            float4 be = *(const float4*)(beta + c);
            float4 o4;
            o4.x = (v[4*i4+0] - mu) * rs * g4.x + be.x;
            o4.y = (v[4*i4+1] - mu) * rs * g4.y + be.y;
            o4.z = (v[4*i4+2] - mu) * rs * g4.z + be.z;
            o4.w = (v[4*i4+3] - mu) * rs * g4.w + be.w;
            *(float4*)(out + grow * DD + c) = o4;
        }
    }
}

// ---------------------------------------------------------------------------
extern "C" void kernel_launch(void* const* d_in, const int* in_sizes, int n_in,
                              void* d_out, int out_size, void* d_ws, size_t ws_size,
                              hipStream_t stream) {
    const float* feat    = (const float*)d_in[0];
    const float* weights = (const float*)d_in[1];
    const float* w1      = (const float*)d_in[2];
    const float* b1      = (const float*)d_in[3];
    const float* w2      = (const float*)d_in[4];
    const float* b2      = (const float*)d_in[5];
    const float* gamma   = (const float*)d_in[6];
    const float* beta    = (const float*)d_in[7];
    float* out = (float*)d_out;

    float* sigw = (float*)d_ws;                 // 64
    float* invn = sigw + 64;                    // 57600
    float* tsum = invn + BB * TT * NN;          // 192*64 = 12288
    f16*   w1f  = (f16*)(tsum + BB * TT * DD);  // 4096 f16
    f16*   w2f  = w1f + 4096;                   // 4096 f16
    float* Mt   = (float*)(w2f + 4096);         // 192*4096 floats

    k_pm<<<BB * TT + 1, 512, 0, stream>>>(feat, weights, w1, w2, sigw, invn,
                                          tsum, w1f, w2f, Mt);
    k_U<<<NW * 5, 256, 0, stream>>>(feat, sigw, invn, tsum, Mt, w1f, w2f,
                                    b1, b2, gamma, beta, out);
}